// Round 11
// baseline (383.825 us; speedup 1.0000x reference)
//
#include <hip/hip_runtime.h>

// HeteroGraphSage on MI355X — round 11: decoupled-lookback single-pass scan
// + quarter-wave gather (4 edges/wave-iter, uint2 feature quads).
//   neigh64[a] = sum_e w_e * x_m[src_e] ; sumw[a] = sum_e w_e
//   h_a = relu( Wcomb @ [x_a | neigh64] + sumw*vbr + beff )
//   out = sigmoid(Wo . h_a + bo)
// Lessons: R7 — edge phases need huge TLP; R8 — cursor contention dominates
// scatter; R9 — XCD-partitioned commit helps; R10 — harness poison fill
// (~60us/400MB) tops the profile, fixed overhead.

typedef __attribute__((ext_vector_type(8))) short short8;
typedef __attribute__((ext_vector_type(4))) float f32x4;

#define PSH 12   // accounts-per-chunk shift for XCD partitioning (4096)

__device__ inline unsigned short f32_bf16(float f) {
  unsigned int u = __float_as_uint(f);
  u += 0x7FFF + ((u >> 16) & 1);   // round-to-nearest-even
  return (unsigned short)(u >> 16);
}
__device__ inline unsigned int pk_bf16(float a, float b) {
  return (unsigned int)f32_bf16(a) | ((unsigned int)f32_bf16(b) << 16);
}

// ---- merged setup: [cvt_xm | hist | prep] by blockIdx range ----------------
__global__ __launch_bounds__(256) void setup_kernel(
    const float* __restrict__ xm, unsigned int* __restrict__ xmbf, int npairs,
    const int* __restrict__ dst, int* __restrict__ counts, int E,
    const float* __restrict__ Wp_a, const float* __restrict__ bp_a,
    const float* __restrict__ Wr_ma, const float* __restrict__ br_ma,
    const float* __restrict__ Wc_a, const float* __restrict__ bc_a,
    unsigned short* __restrict__ Wcomb, float* __restrict__ beff,
    float* __restrict__ vbr, int nb_cvt, int nb_hist) {
  __shared__ float wc_s[256];
  int b = blockIdx.x;
  int t = threadIdx.x;
  if (b < nb_cvt) {
    int i = b * 256 + t;
    if (i < npairs) {
      float2 v = ((const float2*)xm)[i];
      xmbf[i] = pk_bf16(v.x, v.y);
    }
    return;
  }
  b -= nb_cvt;
  if (b < nb_hist) {
    int e = b * 256 + t;
    if (e < E) atomicAdd(&counts[dst[e]], 1);
    return;
  }
  int col = b - nb_hist;   // 0..127: weight folding
  wc_s[t] = Wc_a[col * 256 + t];
  __syncthreads();
  int wave = t >> 6, lane = t & 63;
  if (wave < 2) {
    int k = t;   // 0..127
    float acc = 0.f;
#pragma unroll
    for (int j = 0; j < 128; j += 4) {
      float a0 = Wp_a[(j + 0) * 128 + k];
      float a1 = Wp_a[(j + 1) * 128 + k];
      float a2 = Wp_a[(j + 2) * 128 + k];
      float a3 = Wp_a[(j + 3) * 128 + k];
      acc += wc_s[j] * a0 + wc_s[j + 1] * a1 + wc_s[j + 2] * a2 + wc_s[j + 3] * a3;
    }
    Wcomb[col * 192 + k] = f32_bf16(acc);
  } else if (wave == 2) {
    int kk = lane;   // 0..63
    float acc = 0.f;
#pragma unroll
    for (int j = 0; j < 128; j += 4) {
      float a0 = Wr_ma[(j + 0) * 64 + kk];
      float a1 = Wr_ma[(j + 1) * 64 + kk];
      float a2 = Wr_ma[(j + 2) * 64 + kk];
      float a3 = Wr_ma[(j + 3) * 64 + kk];
      acc += wc_s[128 + j] * a0 + wc_s[129 + j] * a1 + wc_s[130 + j] * a2 + wc_s[131 + j] * a3;
    }
    Wcomb[col * 192 + 128 + kk] = f32_bf16(acc);
  } else {
    float v1 = wc_s[lane] * bp_a[lane] + wc_s[lane + 64] * bp_a[lane + 64];
    float v2 = wc_s[128 + lane] * br_ma[lane] + wc_s[192 + lane] * br_ma[lane + 64];
#pragma unroll
    for (int m = 1; m <= 32; m <<= 1) {
      v1 += __shfl_xor(v1, m, 64);
      v2 += __shfl_xor(v2, m, 64);
    }
    if (lane == 0) { beff[col] = v1 + bc_a[col]; vbr[col] = v2; }
  }
}

// ---- single-pass decoupled-lookback exclusive scan -------------------------
// Ticket ordering guarantees predecessors are already resident (no deadlock).
// status[b] = state<<32 | sum  (state: 0=invalid, 1=aggregate, 2=inclusive).
__global__ __launch_bounds__(256) void scan_kernel(
    const int* __restrict__ counts, int* __restrict__ rowstart,
    int* __restrict__ cursor, unsigned long long* __restrict__ status,
    int* __restrict__ ticket, int NA) {
  __shared__ int tmp[256];
  __shared__ int sh_bid, sh_prev;
  int t = threadIdx.x;
  if (t == 0) sh_bid = atomicAdd(ticket, 1);
  __syncthreads();
  int bid = sh_bid;
  int i = bid * 256 + t;
  int v = (i < NA) ? counts[i] : 0;
  tmp[t] = v;
  __syncthreads();
  for (int off = 1; off < 256; off <<= 1) {
    int x = (t >= off) ? tmp[t - off] : 0;
    __syncthreads();
    tmp[t] += x;
    __syncthreads();
  }
  int incl = tmp[t];
  int aggregate = tmp[255];
  if (t == 0) {
    if (bid == 0) {
      atomicExch(&status[0], (2ULL << 32) | (unsigned int)aggregate);
      sh_prev = 0;
    } else {
      atomicExch(&status[bid], (1ULL << 32) | (unsigned int)aggregate);
      int prev = 0;
      int j = bid - 1;
      while (j >= 0) {
        unsigned long long s;
        do { s = atomicAdd(&status[j], 0ULL); } while ((s >> 32) == 0ULL);
        prev += (int)(unsigned int)s;
        if ((s >> 32) == 2ULL) break;
        --j;
      }
      sh_prev = prev;
      atomicExch(&status[bid], (2ULL << 32) | (unsigned int)(prev + aggregate));
    }
  }
  __syncthreads();
  int excl = sh_prev + incl - v;
  if (i < NA) { rowstart[i] = excl; cursor[i] = excl; }
  else if (i == NA) { rowstart[NA] = excl; }
}

// ---- XCD-partitioned exact-CSR scatter, 4-byte records ---------------------
// record: [wq:15b << 17 | src:17b]; w in [0,1) -> q = w*32768, err <= 3e-5.
__global__ void scatter_kernel(const int* __restrict__ src, const int* __restrict__ dst,
                               const float* __restrict__ w, int* __restrict__ cursor,
                               unsigned int* __restrict__ edges, int E) {
  int slice = blockIdx.x >> 3;
  int p = blockIdx.x & 7;
  int e = slice * 256 + threadIdx.x;
  if (e >= E) return;
  int d = dst[e];
  if (((d >> PSH) & 7) != p) return;
  int pos = atomicAdd(&cursor[d], 1);
  unsigned int q = (unsigned int)fminf(w[e] * 32768.0f, 32767.0f);
  edges[pos] = (unsigned int)src[e] | (q << 17);
}

// ---- neigh gather: one wave/row, QUARTER-wave per edge (4 edges/iter) ------
// lane = q*16 + l: quarter q takes edge e0+q; lane handles feature quad
// 4l..4l+3 via one uint2. Cross-quarter reduce = shfl_xor(16) + shfl_xor(32);
// per-quarter ws duplicates collapse exactly in that reduction.
__global__ __launch_bounds__(256) void gather_kernel(
    const unsigned int* __restrict__ xmbf, const unsigned int* __restrict__ edges,
    const int* __restrict__ rowstart, unsigned int* __restrict__ neighbf,
    float* __restrict__ sumw, int NA) {
  int wave = threadIdx.x >> 6, lane = threadIdx.x & 63;
  int a = blockIdx.x * 4 + wave;
  if (a >= NA) return;
  int q = lane >> 4;      // quarter -> which edge of the 4
  int l = lane & 15;      // feature quad: feats 4l..4l+3
  int s0 = rowstart[a], s1 = rowstart[a + 1];
  float a0 = 0.f, a1 = 0.f, a2 = 0.f, a3 = 0.f, ws = 0.f;
  const float wscale = 1.0f / 32768.0f;
  for (int e0 = s0; e0 < s1; e0 += 8) {
#pragma unroll
    for (int k = 0; k < 2; ++k) {
      int e = e0 + k * 4 + q;
      bool valid = e < s1;
      unsigned int p = edges[valid ? e : s0];
      float w = valid ? (float)(p >> 17) * wscale : 0.f;
      unsigned int s = p & 0x1ffffu;
      uint2 xp = ((const uint2*)(xmbf + (size_t)s * 32))[l];
      a0 += w * __uint_as_float(xp.x << 16);
      a1 += w * __uint_as_float(xp.x & 0xffff0000u);
      a2 += w * __uint_as_float(xp.y << 16);
      a3 += w * __uint_as_float(xp.y & 0xffff0000u);
      ws += w;
    }
  }
  a0 += __shfl_xor(a0, 16, 64); a1 += __shfl_xor(a1, 16, 64);
  a2 += __shfl_xor(a2, 16, 64); a3 += __shfl_xor(a3, 16, 64);
  ws += __shfl_xor(ws, 16, 64);
  a0 += __shfl_xor(a0, 32, 64); a1 += __shfl_xor(a1, 32, 64);
  a2 += __shfl_xor(a2, 32, 64); a3 += __shfl_xor(a3, 32, 64);
  ws += __shfl_xor(ws, 32, 64);
  if (q == 0) {
    uint2 o;
    o.x = pk_bf16(a0, a1);
    o.y = pk_bf16(a2, a3);
    ((uint2*)(neighbf + (size_t)a * 32))[l] = o;
    if (l == 0) sumw[a] = ws;
  }
}

// ---- fused account GEMM + head (round-3 structure) -------------------------
__global__ __launch_bounds__(256) void acct_kernel(
    const float* __restrict__ xa, const unsigned int* __restrict__ neighbf,
    const float* __restrict__ sumw, const unsigned int* __restrict__ Wcomb32,
    const float* __restrict__ beff, const float* __restrict__ vbr,
    const float* __restrict__ Wo, const float* __restrict__ bo,
    float* __restrict__ out, int NA) {
  __shared__ unsigned int B_lds[24 * 128 * 4];   // 48 KB
  int tid = threadIdx.x;
#pragma unroll
  for (int it = 0; it < 12; ++it) {
    int i = tid + it * 256;
    int c = i >> 7, col = i & 127;
    uint4 v = ((const uint4*)Wcomb32)[col * 24 + c];
    *((uint4*)&B_lds[i * 4]) = v;
  }
  __syncthreads();

  int wave = tid >> 6, lane = tid & 63;
  int n15 = lane & 15, quad = lane >> 4;
  float bo0 = bo[0];

  union U4 { uint4 u; short8 h; };

#pragma unroll
  for (int tile = 0; tile < 2; ++tile) {
    int rowbase = blockIdx.x * 128 + (wave * 2 + tile) * 16;
    int m = rowbase + n15;
    int mc = min(m, NA - 1);

    U4 afr[6];
    const float* xrow = xa + (size_t)mc * 128 + quad * 8;
#pragma unroll
    for (int s = 0; s < 4; ++s) {
      float4 f0 = ((const float4*)(xrow + s * 32))[0];
      float4 f1 = ((const float4*)(xrow + s * 32))[1];
      afr[s].u = make_uint4(pk_bf16(f0.x, f0.y), pk_bf16(f0.z, f0.w),
                            pk_bf16(f1.x, f1.y), pk_bf16(f1.z, f1.w));
    }
#pragma unroll
    for (int s = 0; s < 2; ++s) {
      afr[4 + s].u = ((const uint4*)(neighbf + (size_t)mc * 32))[s * 4 + quad];
    }

    f32x4 acc[8];
#pragma unroll
    for (int t = 0; t < 8; ++t) acc[t] = (f32x4){0.f, 0.f, 0.f, 0.f};

#pragma unroll
    for (int s = 0; s < 6; ++s) {
#pragma unroll
      for (int t = 0; t < 8; ++t) {
        U4 bfr;
        bfr.u = *((const uint4*)&B_lds[((s * 4 + quad) * 128 + t * 16 + n15) * 4]);
        acc[t] = __builtin_amdgcn_mfma_f32_16x16x32_bf16(afr[s].h, bfr.h, acc[t], 0, 0, 0);
      }
    }

    float sw[4];
#pragma unroll
    for (int r = 0; r < 4; ++r) {
      int grow = rowbase + quad * 4 + r;
      sw[r] = (grow < NA) ? sumw[grow] : 0.f;
    }
    float rowsum[4] = {0.f, 0.f, 0.f, 0.f};
#pragma unroll
    for (int t = 0; t < 8; ++t) {
      int col = t * 16 + n15;
      float be = beff[col], vb = vbr[col], wo = Wo[col];
#pragma unroll
      for (int r = 0; r < 4; ++r) {
        float h = acc[t][r] + be + sw[r] * vb;
        h = fmaxf(h, 0.f);
        rowsum[r] += h * wo;
      }
    }
#pragma unroll
    for (int msk = 1; msk <= 8; msk <<= 1) {
#pragma unroll
      for (int r = 0; r < 4; ++r) rowsum[r] += __shfl_xor(rowsum[r], msk, 64);
    }
    if (n15 == 0) {
#pragma unroll
      for (int r = 0; r < 4; ++r) {
        int grow = rowbase + quad * 4 + r;
        if (grow < NA) out[grow] = 1.0f / (1.0f + __expf(-(rowsum[r] + bo0)));
      }
    }
  }
}

extern "C" void kernel_launch(void* const* d_in, const int* in_sizes, int n_in,
                              void* d_out, int out_size, void* d_ws, size_t ws_size,
                              hipStream_t stream) {
  const float* xa      = (const float*)d_in[0];
  const float* xm      = (const float*)d_in[1];
  const int*   ema_src = (const int*)d_in[5];
  const int*   ema_dst = (const int*)d_in[6];
  const float* ema_w   = (const float*)d_in[7];
  const float* Wp_a    = (const float*)d_in[8];
  const float* bp_a    = (const float*)d_in[9];
  const float* Wr_ma   = (const float*)d_in[14];
  const float* br_ma   = (const float*)d_in[15];
  const float* Wc_a    = (const float*)d_in[16];
  const float* bc_a    = (const float*)d_in[17];
  const float* Wo      = (const float*)d_in[20];
  const float* bo      = (const float*)d_in[21];

  int NA = in_sizes[0] / 128;
  int NM = in_sizes[1] / 64;
  int E  = in_sizes[5];

  char* ws = (char*)d_ws;
  size_t off = 0;
  auto take = [&](size_t bytes) { char* p = ws + off; off = (off + bytes + 255) & ~(size_t)255; return p; };
  unsigned int* neighbf = (unsigned int*)take((size_t)NA * 32 * 4);      // bf16 pairs [NA][32]
  unsigned int* xmbf    = (unsigned int*)take((size_t)NM * 32 * 4);      // bf16 pairs [NM][32]
  float* sumw           = (float*)take((size_t)NA * 4);
  // ---- zero-init region (single memset): counts | status | ticket ----
  size_t zoff0 = off;
  int nb_scan = (NA + 256) / 256;   // covers NA+1 scan positions
  int* counts           = (int*)take((size_t)NA * 4);
  unsigned long long* status = (unsigned long long*)take((size_t)nb_scan * 8);
  int* ticket           = (int*)take(256);
  size_t zlen = off - zoff0;
  // --------------------------------------------------------------------
  int* rowstart         = (int*)take((size_t)(NA + 1) * 4);
  int* cursor           = (int*)take((size_t)NA * 4);
  unsigned int* edges   = (unsigned int*)take((size_t)E * 4);
  unsigned short* Wcomb = (unsigned short*)take(128 * 192 * 2);
  float* beff           = (float*)take(128 * 4);
  float* vbr            = (float*)take(128 * 4);

  hipMemsetAsync(ws + zoff0, 0, zlen, stream);

  int npairs = NM * 32;
  int nb_cvt = (npairs + 255) / 256;
  int nb_hist = (E + 255) / 256;
  setup_kernel<<<nb_cvt + nb_hist + 128, 256, 0, stream>>>(
      xm, xmbf, npairs, ema_dst, counts, E,
      Wp_a, bp_a, Wr_ma, br_ma, Wc_a, bc_a, Wcomb, beff, vbr, nb_cvt, nb_hist);

  scan_kernel<<<nb_scan, 256, 0, stream>>>(counts, rowstart, cursor, status, ticket, NA);

  scatter_kernel<<<nb_hist * 8, 256, 0, stream>>>(ema_src, ema_dst, ema_w, cursor, edges, E);

  int gb = (NA + 3) / 4;
  gather_kernel<<<gb, 256, 0, stream>>>(xmbf, edges, rowstart, neighbf, sumw, NA);

  int ab = (NA + 127) / 128;
  acct_kernel<<<ab, 256, 0, stream>>>(xa, neighbf, sumw, (const unsigned int*)Wcomb,
                                      beff, vbr, Wo, bo, (float*)d_out, NA);
}